// Round 16
// baseline (226.865 us; speedup 1.0000x reference)
//
#include <hip/hip_runtime.h>
#include <math.h>

#define NTOK 8192
#define HD   2048
#define OD   1024
#define NE   8
#define CTXD 4096
#define CH   64

typedef short bf16x8 __attribute__((ext_vector_type(8)));
typedef float f32x4  __attribute__((ext_vector_type(4)));

static const size_t OFF_VN = (size_t)NTOK * OD;                 // v_next
static const size_t OFF_RP = 2 * (size_t)NTOK * OD;             // router_probs
static const size_t OFF_TI = OFF_RP + (size_t)NTOK * NE;        // top_k_idx
static const size_t OFF_TP = OFF_TI + (size_t)NTOK * 2;         // top_k_probs

// ---- ws byte offsets ----
#define WS_PCNT   0
#define WS_TOTAL  256
#define WS_TABLE  512
#define WS_PLIST  8192
#define WS_PWTS   (8192 + 64*NTOK*4)
#define WS_W1P    (WS_PWTS + 64*NTOK*8)
#define WS_W2P    (WS_W1P + NE*CTXD*CH*2)

__device__ __forceinline__ unsigned bfpack2(float a, float b) {
    unsigned ua = __float_as_uint(a), ub = __float_as_uint(b);
    ua = (ua + 0x7FFFu + ((ua >> 16) & 1u)) >> 16;
    ub = (ub + 0x7FFFu + ((ub >> 16) & 1u)) >> 16;
    return ua | (ub << 16);
}
__device__ __forceinline__ unsigned short bf1(float a) {
    unsigned ua = __float_as_uint(a);
    return (unsigned short)((ua + 0x7FFFu + ((ua >> 16) & 1u)) >> 16);
}
__device__ __forceinline__ float fsigmoid(float z) {
    return __fdividef(1.f, 1.f + __expf(-z));
}
__device__ __forceinline__ float fsoftplus(float z) {
    return fmaxf(z, 0.f) + __logf(1.f + __expf(-fabsf(z)));
}

// ---------------- pre-pass: W1 | W2 | router (router LAST, warms h for moe)
// blocks [0,1024): W1 -> W1p [8][512][64][8]
// blocks [1024,1792): W2 -> W2p [8][8][3072][8]
// blocks [1792,3840): router, 4 tokens/block (r2-proven structure)
__global__ __launch_bounds__(256) void pre_kernel(
    const float* __restrict__ h, const float* __restrict__ rw,
    const float* __restrict__ rb,
    const float* __restrict__ W1, const float* __restrict__ W2,
    unsigned short* __restrict__ W1p, unsigned short* __restrict__ W2p,
    float* __restrict__ out,
    int* __restrict__ pcnt, int* __restrict__ plist, float2* __restrict__ pwts)
{
    int bb = blockIdx.x;
    int tid = threadIdx.x;
    if (bb < 1024) {
        int flat = bb * 256 + tid;
        int e = flat >> 15, rem = flat & 32767;
        int kb = rem >> 6, c = rem & 63;
        const float* src = W1 + (size_t)e * CTXD * CH + (size_t)kb * 8 * CH + c;
        uint4 o;
        o.x = bfpack2(src[0 * 64], src[1 * 64]);
        o.y = bfpack2(src[2 * 64], src[3 * 64]);
        o.z = bfpack2(src[4 * 64], src[5 * 64]);
        o.w = bfpack2(src[6 * 64], src[7 * 64]);
        *(uint4*)(W1p + (size_t)flat * 8) = o;
        return;
    }
    if (bb < 1792) {
        int flat = (bb - 1024) * 256 + tid;
        int e = flat / 24576, rem = flat - e * 24576;
        int kb = rem / 3072, c = rem - kb * 3072;
        const float* src = W2 + ((size_t)e * CH + kb * 8) * (3 * OD) + c;
        uint4 o;
        o.x = bfpack2(src[0 * 3072], src[1 * 3072]);
        o.y = bfpack2(src[2 * 3072], src[3 * 3072]);
        o.z = bfpack2(src[4 * 3072], src[5 * 3072]);
        o.w = bfpack2(src[6 * 3072], src[7 * 3072]);
        *(uint4*)(W2p + (size_t)flat * 8) = o;
        return;
    }
    // ---- router: 4 waves/block, one token per wave ----
    int lane = tid & 63;
    int wv   = tid >> 6;
    int b    = (bb - 1792) * 4 + wv;
    const float4* h4 = (const float4*)(h + (size_t)b * HD);

    float a0=0.f,a1=0.f,a2=0.f,a3=0.f,a4=0.f,a5=0.f,a6=0.f,a7=0.f;
    #pragma unroll
    for (int i = 0; i < 8; i++) {
        int k4 = i * 64 + lane;
        float4 hv = h4[k4];
        const float4* wr = (const float4*)rw + (size_t)k4 * 8;
        float4 w00 = wr[0], w01 = wr[1];
        float4 w10 = wr[2], w11 = wr[3];
        float4 w20 = wr[4], w21 = wr[5];
        float4 w30 = wr[6], w31 = wr[7];
        a0 = fmaf(hv.x,w00.x,fmaf(hv.y,w10.x,fmaf(hv.z,w20.x,fmaf(hv.w,w30.x,a0))));
        a1 = fmaf(hv.x,w00.y,fmaf(hv.y,w10.y,fmaf(hv.z,w20.y,fmaf(hv.w,w30.y,a1))));
        a2 = fmaf(hv.x,w00.z,fmaf(hv.y,w10.z,fmaf(hv.z,w20.z,fmaf(hv.w,w30.z,a2))));
        a3 = fmaf(hv.x,w00.w,fmaf(hv.y,w10.w,fmaf(hv.z,w20.w,fmaf(hv.w,w30.w,a3))));
        a4 = fmaf(hv.x,w01.x,fmaf(hv.y,w11.x,fmaf(hv.z,w21.x,fmaf(hv.w,w31.x,a4))));
        a5 = fmaf(hv.x,w01.y,fmaf(hv.y,w11.y,fmaf(hv.z,w21.y,fmaf(hv.w,w31.y,a5))));
        a6 = fmaf(hv.x,w01.z,fmaf(hv.y,w11.z,fmaf(hv.z,w21.z,fmaf(hv.w,w31.z,a6))));
        a7 = fmaf(hv.x,w01.w,fmaf(hv.y,w11.w,fmaf(hv.z,w21.w,fmaf(hv.w,w31.w,a7))));
    }
    #pragma unroll
    for (int off = 32; off >= 1; off >>= 1) {
        a0 += __shfl_xor(a0, off); a1 += __shfl_xor(a1, off);
        a2 += __shfl_xor(a2, off); a3 += __shfl_xor(a3, off);
        a4 += __shfl_xor(a4, off); a5 += __shfl_xor(a5, off);
        a6 += __shfl_xor(a6, off); a7 += __shfl_xor(a7, off);
    }
    if (lane == 0) {
        float lg[8] = {a0+rb[0], a1+rb[1], a2+rb[2], a3+rb[3],
                       a4+rb[4], a5+rb[5], a6+rb[6], a7+rb[7]};
        float m = lg[0];
        #pragma unroll
        for (int e2 = 1; e2 < 8; e2++) m = fmaxf(m, lg[e2]);
        float p[8]; float s = 0.f;
        #pragma unroll
        for (int e2 = 0; e2 < 8; e2++) { p[e2] = expf(lg[e2] - m); s += p[e2]; }
        float inv = 1.f / s;
        #pragma unroll
        for (int e2 = 0; e2 < 8; e2++) {
            p[e2] *= inv;
            out[OFF_RP + (size_t)b * 8 + e2] = p[e2];
        }
        int e0 = 0;
        #pragma unroll
        for (int e2 = 1; e2 < 8; e2++) if (p[e2] > p[e0]) e0 = e2;
        int e1 = (e0 == 0) ? 1 : 0;
        #pragma unroll
        for (int e2 = 0; e2 < 8; e2++) {
            if (e2 == e0) continue;
            if (p[e2] > p[e1]) e1 = e2;
        }
        float s2 = p[e0] + p[e1];
        float w0 = p[e0] / s2, w1 = p[e1] / s2;
        out[OFF_TI + (size_t)b*2 + 0] = (float)e0;
        out[OFF_TI + (size_t)b*2 + 1] = (float)e1;
        out[OFF_TP + (size_t)b*2 + 0] = w0;
        out[OFF_TP + (size_t)b*2 + 1] = w1;
        int lo = min(e0, e1), hi = max(e0, e1);
        float wlo = (e0 < e1) ? w0 : w1;
        float whi = (e0 < e1) ? w1 : w0;
        int pid = lo * 8 + hi;
        int pos = atomicAdd(&pcnt[pid], 1);
        plist[pid * NTOK + pos] = b;
        pwts[pid * NTOK + pos] = make_float2(wlo, whi);
    }
}

// ---------------- prefix: pid counts -> dense 16-token tile table
__global__ void prefix_kernel(const int* __restrict__ pcnt,
                              int* __restrict__ table, int* __restrict__ total) {
    int tid = threadIdx.x;
    int cnt = pcnt[tid];
    int tiles = (cnt + 15) >> 4;
    int incl = tiles;
    #pragma unroll
    for (int off = 1; off < 64; off <<= 1) {
        int v = __shfl_up(incl, off);
        if (tid >= off) incl += v;
    }
    int base = incl - tiles;
    for (int i = 0; i < tiles; i++) table[base + i] = tid | (i << 6);
    if (tid == 63) *total = incl;
}

// ---------------- MoE: reg-staged fp32->bf16 dbuf stage-1 (no ctxb), full-K acc
__global__ __launch_bounds__(512, 4) void moe_kernel(
    const float* __restrict__ h, const float* __restrict__ x,
    const float* __restrict__ v, const float* __restrict__ mu,
    const float* __restrict__ b1, const float* __restrict__ b2,
    const unsigned short* __restrict__ W1p, const unsigned short* __restrict__ W2p,
    const int* __restrict__ pcnt, const int* __restrict__ table,
    const int* __restrict__ total, const int* __restrict__ plist,
    const float2* __restrict__ pwts, float* __restrict__ out)
{
    __shared__ unsigned short abuf[2][8192];     // dbuf A-tile chunk 16tok x 512c (2x16KB)
    __shared__ unsigned short hid_s[16 * 128];   // swizzled bf16 [16 tok][2*64]  4 KB
    __shared__ int    toks[16];
    __shared__ float2 tw[16];

    int bid = (blockIdx.x & 7) * 72 + (blockIdx.x >> 3);   // XCD-chunked, 576=8*72
    if (bid >= *total) return;
    int entry = table[bid];
    int pid = entry & 63;
    int start = (entry >> 6) * 16;
    int lo = pid >> 3, hi = pid & 7;
    int cnt = pcnt[pid];
    int nt = cnt - start; if (nt > 16) nt = 16;

    int tid = threadIdx.x;
    if (tid < 16) {
        int idx = start + (tid < nt ? tid : 0);
        toks[tid] = plist[pid * NTOK + idx];
        tw[tid]   = pwts[pid * NTOK + idx];
    }
    __syncthreads();

    int lane = tid & 63, w = tid >> 6;           // 8 waves
    int l15 = lane & 15, lq = lane >> 4;

    // stage-1 wave roles: (expert slot, col-group); full-K accumulation
    int s1s = w >> 2;                            // 0 = lo, 1 = hi
    int cg  = w & 3;                             // 16-col group within expert's 64
    int myE = s1s ? hi : lo;
    int colw = cg * 16 + l15;
    const unsigned short* W1e = W1p + (size_t)myE * (CTXD * CH);

    // staging map: thread covers 16 fp32 of one token row per chunk
    int st_row = tid >> 5;                       // token row 0..15
    int st_seg = tid & 31;                       // 16-float segment within 512 cols
    int st_tok = toks[st_row];
    const float* hsrc = h + (size_t)st_tok * HD;
    const float* xsrc = x + (size_t)st_tok * OD;
    const float* vsrc = v + (size_t)st_tok * OD;
    int inrow = st_seg * 32;                     // byte offset within row (bf16)
    int wbx0 = st_row * 1024 + ((inrow     ) ^ ((st_row & 7) << 4));
    int wbx1 = st_row * 1024 + ((inrow + 16) ^ ((st_row & 7) << 4));

    float4 ld0, ld1, ld2, ld3;

#define LOADC(C) do {                                                          \
        const float* s_;                                                       \
        if ((C) < 4)      s_ = hsrc + (C) * 512;                               \
        else if ((C) < 6) s_ = xsrc + ((C) - 4) * 512;                         \
        else              s_ = vsrc + ((C) - 6) * 512;                         \
        s_ += st_seg * 16;                                                     \
        ld0 = ((const float4*)s_)[0]; ld1 = ((const float4*)s_)[1];            \
        ld2 = ((const float4*)s_)[2]; ld3 = ((const float4*)s_)[3];            \
    } while (0)

#define PACKW(BUF) do {                                                        \
        uint4 p0, p1;                                                          \
        p0.x = bfpack2(ld0.x, ld0.y); p0.y = bfpack2(ld0.z, ld0.w);            \
        p0.z = bfpack2(ld1.x, ld1.y); p0.w = bfpack2(ld1.z, ld1.w);            \
        p1.x = bfpack2(ld2.x, ld2.y); p1.y = bfpack2(ld2.z, ld2.w);            \
        p1.z = bfpack2(ld3.x, ld3.y); p1.w = bfpack2(ld3.z, ld3.w);            \
        *(uint4*)((char*)abuf[BUF] + wbx0) = p0;                               \
        *(uint4*)((char*)abuf[BUF] + wbx1) = p1;                               \
    } while (0)

    f32x4 acc = {0.f, 0.f, 0.f, 0.f};

    LOADC(0); PACKW(0);
    __syncthreads();
    #pragma unroll 1
    for (int kc = 0; kc < 8; kc++) {
        int cur = kc & 1;
        if (kc < 7) LOADC(kc + 1);               // issue early; hides under MFMA
        #pragma unroll
        for (int ks = 0; ks < 16; ks++) {
            int phys = (ks * 64 + lq * 16) ^ ((l15 & 7) << 4);
            bf16x8 a = *(const bf16x8*)((const char*)abuf[cur] + l15 * 1024 + phys);
            int kb = kc * 64 + ks * 4 + lq;
            bf16x8 b = *(const bf16x8*)(W1e + ((size_t)kb * 64 + colw) * 8);
            acc = __builtin_amdgcn_mfma_f32_16x16x32_bf16(a, b, acc, 0, 0, 0);
        }
        if (kc < 7) PACKW(cur ^ 1);              // write-late into other buffer
        __syncthreads();
    }
#undef LOADC
#undef PACKW

    // relu + bias -> hid LDS (bf16, swizzled). C layout: col=l15, row=lq*4+i
    {
        float b1v = b1[myE * CH + colw];
        int colh = s1s * 64 + colw;
        #pragma unroll
        for (int i = 0; i < 4; i++) {
            int r0 = lq * 4 + i;
            float hv = acc[i] + b1v; hv = hv > 0.f ? hv : 0.f;
            int by = (r0 * 256 + colh * 2) ^ ((r0 & 7) << 4);
            *(unsigned short*)((char*)hid_s + by) = bf1(hv);
        }
    }
    __syncthreads();

    // ---- stage 2: wave w owns o-band [w*128, w*128+128)
    bf16x8 af[2][2];
    #pragma unroll
    for (int s = 0; s < 2; s++)
        #pragma unroll
        for (int ks = 0; ks < 2; ks++) {
            int col = s * 64 + ks * 32 + lq * 8;
            int by = (l15 * 256 + col * 2) ^ ((l15 & 7) << 4);
            af[s][ks] = *(const bf16x8*)((const char*)hid_s + by);
        }

    const unsigned short* W2lo = W2p + (size_t)lo * (CH * 3 * OD);
    const unsigned short* W2hi = W2p + (size_t)hi * (CH * 3 * OD);
    const float* b2lo = b2 + (size_t)lo * 3072;
    const float* b2hi = b2 + (size_t)hi * 3072;

    int   tok_r[4];
    float twx[4], twy[4];
    #pragma unroll
    for (int i = 0; i < 4; i++) {
        int trow = lq * 4 + i;
        tok_r[i] = toks[trow];
        float2 t2 = tw[trow];
        twx[i] = t2.x; twy[i] = t2.y;
    }

    for (int ot = 0; ot < 8; ot++) {
        int o = w * 128 + ot * 16 + l15;
        float xo[4], vo[4];
        #pragma unroll
        for (int i = 0; i < 4; i++) {
            size_t off = (size_t)tok_r[i] * OD + o;
            xo[i] = x[off];
            vo[i] = v[off];
        }
        float muo = mu[o];
        float accVN[4] = {0.f,0.f,0.f,0.f};
        float accGV[4] = {0.f,0.f,0.f,0.f};

        #pragma unroll
        for (int s = 0; s < 2; s++) {
            const unsigned short* W2e = s ? W2hi : W2lo;
            const float* b2e = s ? b2hi : b2lo;
            f32x4 aA = {0.f,0.f,0.f,0.f};
            f32x4 aB = {0.f,0.f,0.f,0.f};
            f32x4 aG = {0.f,0.f,0.f,0.f};
            #pragma unroll
            for (int ks = 0; ks < 2; ks++) {
                int kb = ks * 4 + lq;
                bf16x8 wA = *(const bf16x8*)(W2e + ((size_t)kb * 3072 + o) * 8);
                bf16x8 wB = *(const bf16x8*)(W2e + ((size_t)kb * 3072 + OD + o) * 8);
                bf16x8 wG = *(const bf16x8*)(W2e + ((size_t)kb * 3072 + 2 * OD + o) * 8);
                aA = __builtin_amdgcn_mfma_f32_16x16x32_bf16(af[s][ks], wA, aA, 0, 0, 0);
                aB = __builtin_amdgcn_mfma_f32_16x16x32_bf16(af[s][ks], wB, aB, 0, 0, 0);
                aG = __builtin_amdgcn_mfma_f32_16x16x32_bf16(af[s][ks], wG, aG, 0, 0, 0);
            }
            float ba = b2e[o], bb = b2e[OD + o], bg = b2e[2 * OD + o];
            #pragma unroll
            for (int i = 0; i < 4; i++) {
                float za = aA[i] + ba;
                float zb = aB[i] + bb;
                float zg = aG[i] + bg;
                float alpha = fsigmoid(za);
                float beta  = fsoftplus(zb);
                float gate  = fsigmoid(zg);
                float ws = s ? twy[i] : twx[i];
                float vn_s = alpha * vo[i] - beta * (xo[i] - muo);
                accVN[i] += ws * vn_s;
                accGV[i] += ws * gate * vn_s;
            }
        }
        #pragma unroll
        for (int i = 0; i < 4; i++) {
            if (lq * 4 + i < nt) {
                size_t off = (size_t)tok_r[i] * OD + o;
                out[off]          = xo[i] + 0.1f * accGV[i];
                out[OFF_VN + off] = accVN[i];
            }
        }
    }
}

extern "C" void kernel_launch(void* const* d_in, const int* in_sizes, int n_in,
                              void* d_out, int out_size, void* d_ws, size_t ws_size,
                              hipStream_t stream)
{
    (void)in_sizes; (void)n_in; (void)out_size; (void)ws_size;
    const float* h  = (const float*)d_in[0];
    const float* x  = (const float*)d_in[1];
    const float* v  = (const float*)d_in[2];
    const float* rw = (const float*)d_in[3];
    const float* rb = (const float*)d_in[4];
    const float* mu = (const float*)d_in[5];
    const float* W1 = (const float*)d_in[6];
    const float* b1 = (const float*)d_in[7];
    const float* W2 = (const float*)d_in[8];
    const float* b2 = (const float*)d_in[9];
    float* out = (float*)d_out;

    char* ws = (char*)d_ws;
    int*    pcnt  = (int*)(ws + WS_PCNT);
    int*    total = (int*)(ws + WS_TOTAL);
    int*    table = (int*)(ws + WS_TABLE);
    int*    plist = (int*)(ws + WS_PLIST);
    float2* pwts  = (float2*)(ws + WS_PWTS);
    unsigned short* W1p = (unsigned short*)(ws + WS_W1P);
    unsigned short* W2p = (unsigned short*)(ws + WS_W2P);

    hipMemsetAsync(pcnt, 0, 64 * sizeof(int), stream);

    pre_kernel<<<3840, 256, 0, stream>>>(h, rw, rb, W1, W2, W1p, W2p,
                                         out, pcnt, plist, pwts);
    prefix_kernel<<<1, 64, 0, stream>>>(pcnt, table, total);
    moe_kernel<<<576, 512, 0, stream>>>(h, x, v, mu, b1, b2, W1p, W2p,
                                        pcnt, table, total, plist, pwts, out);
}

// Round 18
// 197.118 us; speedup vs baseline: 1.1509x; 1.1509x over previous
//
#include <hip/hip_runtime.h>
#include <math.h>

#define NTOK 8192
#define HD   2048
#define OD   1024
#define NE   8
#define CTXD 4096
#define CH   64

typedef short bf16x8 __attribute__((ext_vector_type(8)));
typedef float f32x4  __attribute__((ext_vector_type(4)));

static const size_t OFF_VN = (size_t)NTOK * OD;                 // v_next
static const size_t OFF_RP = 2 * (size_t)NTOK * OD;             // router_probs
static const size_t OFF_TI = OFF_RP + (size_t)NTOK * NE;        // top_k_idx
static const size_t OFF_TP = OFF_TI + (size_t)NTOK * 2;         // top_k_probs

// ---- ws byte offsets (identical to r13 footprint) ----
#define WS_PCNT   0
#define WS_TOTAL  256
#define WS_TABLE  512
#define WS_PLIST  8192
#define WS_PWTS   (8192 + 64*NTOK*4)
#define WS_W1P    (WS_PWTS + 64*NTOK*8)
#define WS_W2P    (WS_W1P + NE*CTXD*CH*2)
#define WS_CTXB   (WS_W2P + NE*CH*3*OD*2)

__device__ __forceinline__ unsigned bfpack2(float a, float b) {
    unsigned ua = __float_as_uint(a), ub = __float_as_uint(b);
    ua = (ua + 0x7FFFu + ((ua >> 16) & 1u)) >> 16;
    ub = (ub + 0x7FFFu + ((ub >> 16) & 1u)) >> 16;
    return ua | (ub << 16);
}
__device__ __forceinline__ unsigned short bf1(float a) {
    unsigned ua = __float_as_uint(a);
    return (unsigned short)((ua + 0x7FFFu + ((ua >> 16) & 1u)) >> 16);
}
__device__ __forceinline__ float fsigmoid(float z) {
    return __fdividef(1.f, 1.f + __expf(-z));
}
__device__ __forceinline__ float fsoftplus(float z) {
    return fmaxf(z, 0.f) + __logf(1.f + __expf(-fabsf(z)));
}
__device__ __forceinline__ void gl_lds16(const void* g, void* l) {
    __builtin_amdgcn_global_load_lds(
        (const __attribute__((address_space(1))) void*)g,
        (__attribute__((address_space(3))) void*)l, 16, 0, 0);
}

// ---------------- fused pre-pass (r13 layout):
// blocks [0,1024): W1 -> W1p [8][512][64][8]
// blocks [1024,1792): W2 -> W2p [8][8][3072][8]
// blocks [1792,3840): one wave per token: ctx->bf16 + coalesced-row router
__global__ __launch_bounds__(256) void pre_kernel(
    const float* __restrict__ h, const float* __restrict__ x,
    const float* __restrict__ v, const float* __restrict__ rw,
    const float* __restrict__ rb,
    const float* __restrict__ W1, const float* __restrict__ W2,
    unsigned short* __restrict__ W1p, unsigned short* __restrict__ W2p,
    unsigned short* __restrict__ ctxb,
    float* __restrict__ out,
    int* __restrict__ pcnt, int* __restrict__ plist, float2* __restrict__ pwts)
{
    int bb = blockIdx.x;
    int tid = threadIdx.x;
    if (bb < 1024) {
        int flat = bb * 256 + tid;
        int e = flat >> 15, rem = flat & 32767;
        int kb = rem >> 6, c = rem & 63;
        const float* src = W1 + (size_t)e * CTXD * CH + (size_t)kb * 8 * CH + c;
        uint4 o;
        o.x = bfpack2(src[0 * 64], src[1 * 64]);
        o.y = bfpack2(src[2 * 64], src[3 * 64]);
        o.z = bfpack2(src[4 * 64], src[5 * 64]);
        o.w = bfpack2(src[6 * 64], src[7 * 64]);
        *(uint4*)(W1p + (size_t)flat * 8) = o;
        return;
    }
    if (bb < 1792) {
        int flat = (bb - 1024) * 256 + tid;
        int e = flat / 24576, rem = flat - e * 24576;
        int kb = rem / 3072, c = rem - kb * 3072;
        const float* src = W2 + ((size_t)e * CH + kb * 8) * (3 * OD) + c;
        uint4 o;
        o.x = bfpack2(src[0 * 3072], src[1 * 3072]);
        o.y = bfpack2(src[2 * 3072], src[3 * 3072]);
        o.z = bfpack2(src[4 * 3072], src[5 * 3072]);
        o.w = bfpack2(src[6 * 3072], src[7 * 3072]);
        *(uint4*)(W2p + (size_t)flat * 8) = o;
        return;
    }
    // ---- ctx -> bf16 + router: one wave per token ----
    int lane = tid & 63;
    int wv   = tid >> 6;
    int t    = (bb - 1792) * 4 + wv;
    const float* hb = h + (size_t)t * HD;
    const float* xb = x + (size_t)t * OD;
    const float* vb = v + (size_t)t * OD;
    unsigned short* cb = ctxb + (size_t)t * CTXD;

    // ctx pack: 16 x float4 per lane, coalesced
    #pragma unroll
    for (int i = 0; i < 16; i++) {
        int col = i * 256 + lane * 4;            // region uniform per i
        float4 f;
        if (i < 8)       f = *(const float4*)(hb + col);
        else if (i < 12) f = *(const float4*)(xb + (col - HD));
        else             f = *(const float4*)(vb + (col - HD - OD));
        uint2 pk = make_uint2(bfpack2(f.x, f.y), bfpack2(f.z, f.w));
        *(uint2*)(cb + col) = pk;
    }

    // router: lane owns rows rr*64+lane; rw row loads at 32B lane-stride
    float r0=0.f,r1=0.f,r2=0.f,r3=0.f,r4=0.f,r5=0.f,r6=0.f,r7=0.f;
    #pragma unroll 8
    for (int rr = 0; rr < 32; rr++) {
        int row = rr * 64 + lane;
        float hv = hb[row];                      // L1-hot (just packed)
        const float4* rwp = (const float4*)(rw + (size_t)row * 8);
        float4 wA = rwp[0], wB = rwp[1];
        r0 = fmaf(hv, wA.x, r0); r1 = fmaf(hv, wA.y, r1);
        r2 = fmaf(hv, wA.z, r2); r3 = fmaf(hv, wA.w, r3);
        r4 = fmaf(hv, wB.x, r4); r5 = fmaf(hv, wB.y, r5);
        r6 = fmaf(hv, wB.z, r6); r7 = fmaf(hv, wB.w, r7);
    }
    #pragma unroll
    for (int off = 32; off >= 1; off >>= 1) {
        r0 += __shfl_xor(r0, off); r1 += __shfl_xor(r1, off);
        r2 += __shfl_xor(r2, off); r3 += __shfl_xor(r3, off);
        r4 += __shfl_xor(r4, off); r5 += __shfl_xor(r5, off);
        r6 += __shfl_xor(r6, off); r7 += __shfl_xor(r7, off);
    }
    if (lane == 0) {
        float lg[8] = {r0+rb[0], r1+rb[1], r2+rb[2], r3+rb[3],
                       r4+rb[4], r5+rb[5], r6+rb[6], r7+rb[7]};
        float m = lg[0];
        #pragma unroll
        for (int e2 = 1; e2 < 8; e2++) m = fmaxf(m, lg[e2]);
        float p[8]; float s = 0.f;
        #pragma unroll
        for (int e2 = 0; e2 < 8; e2++) { p[e2] = expf(lg[e2] - m); s += p[e2]; }
        float inv = 1.f / s;
        #pragma unroll
        for (int e2 = 0; e2 < 8; e2++) {
            p[e2] *= inv;
            out[OFF_RP + (size_t)t * 8 + e2] = p[e2];
        }
        int e0 = 0;
        #pragma unroll
        for (int e2 = 1; e2 < 8; e2++) if (p[e2] > p[e0]) e0 = e2;
        int e1 = (e0 == 0) ? 1 : 0;
        #pragma unroll
        for (int e2 = 0; e2 < 8; e2++) {
            if (e2 == e0) continue;
            if (p[e2] > p[e1]) e1 = e2;
        }
        float s2 = p[e0] + p[e1];
        float w0 = p[e0] / s2, w1 = p[e1] / s2;
        out[OFF_TI + (size_t)t*2 + 0] = (float)e0;
        out[OFF_TI + (size_t)t*2 + 1] = (float)e1;
        out[OFF_TP + (size_t)t*2 + 0] = w0;
        out[OFF_TP + (size_t)t*2 + 1] = w1;
        int lo = min(e0, e1), hi = max(e0, e1);
        float wlo = (e0 < e1) ? w0 : w1;
        float whi = (e0 < e1) ? w1 : w0;
        int pid = lo * 8 + hi;
        int pos = atomicAdd(&pcnt[pid], 1);
        plist[pid * NTOK + pos] = t;
        pwts[pid * NTOK + pos] = make_float2(wlo, whi);
    }
}

// ---------------- prefix: pid counts -> dense 16-token tile table
__global__ void prefix_kernel(const int* __restrict__ pcnt,
                              int* __restrict__ table, int* __restrict__ total) {
    int tid = threadIdx.x;
    int cnt = pcnt[tid];
    int tiles = (cnt + 15) >> 4;
    int incl = tiles;
    #pragma unroll
    for (int off = 1; off < 64; off <<= 1) {
        int v = __shfl_up(incl, off);
        if (tid >= off) incl += v;
    }
    int base = incl - tiles;
    for (int i = 0; i < tiles; i++) table[base + i] = tid | (i << 6);
    if (tid == 63) *total = incl;
}

// ---------------- MoE: global_load_lds double-buffered stage-1, full-K acc
__global__ __launch_bounds__(512, 4) void moe_kernel(
    const float* __restrict__ x, const float* __restrict__ v,
    const float* __restrict__ mu,
    const float* __restrict__ b1, const float* __restrict__ b2,
    const unsigned short* __restrict__ W1p, const unsigned short* __restrict__ W2p,
    const unsigned short* __restrict__ ctxb,
    const int* __restrict__ pcnt, const int* __restrict__ table,
    const int* __restrict__ total, const int* __restrict__ plist,
    const float2* __restrict__ pwts, float* __restrict__ out)
{
    __shared__ unsigned short abuf[2][8192];     // dbuf A-tile chunk 16tok x 512c (2x16KB)
    __shared__ unsigned short hid_s[16 * 128];   // swizzled bf16 [16 tok][2*64]  4 KB
    __shared__ int    toks[16];
    __shared__ float2 tw[16];

    int bid = (blockIdx.x & 7) * 72 + (blockIdx.x >> 3);   // XCD-chunked, 576=8*72
    if (bid >= *total) return;
    int entry = table[bid];
    int pid = entry & 63;
    int start = (entry >> 6) * 16;
    int lo = pid >> 3, hi = pid & 7;
    int cnt = pcnt[pid];
    int nt = cnt - start; if (nt > 16) nt = 16;

    int tid = threadIdx.x;
    if (tid < 16) {
        int idx = start + (tid < nt ? tid : 0);
        toks[tid] = plist[pid * NTOK + idx];
        tw[tid]   = pwts[pid * NTOK + idx];
    }
    __syncthreads();

    int lane = tid & 63, w = tid >> 6;           // 8 waves
    int l15 = lane & 15, lq = lane >> 4;

    // stage-1 wave roles: (expert slot, col-group); full-K accumulation
    int s1s = w >> 2;                            // 0 = lo, 1 = hi
    int cg  = w & 3;                             // 16-col group within expert's 64
    int myE = s1s ? hi : lo;
    int colw = cg * 16 + l15;
    const unsigned short* W1e = W1p + (size_t)myE * (CTXD * CH);

    // staging: per chunk (512 cols), wave w stages token rows 2w, 2w+1
    int wv2 = w * 2;

#define STAGE(KC, BUF) do {                                                    \
        _Pragma("unroll")                                                      \
        for (int j = 0; j < 2; j++) {                                          \
            int r_ = wv2 + j;                                                  \
            int tok_ = toks[r_];                                               \
            int soff_ = ((lane * 16) ^ ((r_ & 7) << 4)) >> 1;                  \
            const unsigned short* gs_ = ctxb + (size_t)tok_ * CTXD             \
                                        + (KC) * 512 + soff_;                  \
            gl_lds16(gs_, (char*)abuf[BUF] + w * 2048 + j * 1024);             \
        }                                                                      \
    } while (0)

#define DRAIN_BAR() do {                                                       \
        asm volatile("s_waitcnt vmcnt(0)" ::: "memory");                       \
        __syncthreads();                                                       \
    } while (0)

    f32x4 acc = {0.f, 0.f, 0.f, 0.f};

    STAGE(0, 0);
    DRAIN_BAR();                                  // buf0 DMA complete for ALL waves
    for (int kc = 0; kc < 8; kc++) {
        int cur = kc & 1;
        if (kc < 7) STAGE(kc + 1, cur ^ 1);       // async DMA, hides under compute
        #pragma unroll
        for (int ks = 0; ks < 16; ks++) {
            int phys = (ks * 64 + lq * 16) ^ ((l15 & 7) << 4);
            bf16x8 a = *(const bf16x8*)((const char*)abuf[cur] + l15 * 1024 + phys);
            int kb = kc * 64 + ks * 4 + lq;
            bf16x8 b = *(const bf16x8*)(W1e + ((size_t)kb * 64 + colw) * 8);
            acc = __builtin_amdgcn_mfma_f32_16x16x32_bf16(a, b, acc, 0, 0, 0);
        }
        DRAIN_BAR();                              // drain prefetch DMA + dbuf guard
    }
#undef STAGE
#undef DRAIN_BAR

    // relu + bias -> hid LDS (bf16, swizzled). C layout: col=l15, row=lq*4+i
    {
        float b1v = b1[myE * CH + colw];
        int colh = s1s * 64 + colw;
        #pragma unroll
        for (int i = 0; i < 4; i++) {
            int r0 = lq * 4 + i;
            float hv = acc[i] + b1v; hv = hv > 0.f ? hv : 0.f;
            int by = (r0 * 256 + colh * 2) ^ ((r0 & 7) << 4);
            *(unsigned short*)((char*)hid_s + by) = bf1(hv);
        }
    }
    __syncthreads();

    // ---- stage 2: wave w owns o-band [w*128, w*128+128)
    bf16x8 af[2][2];
    #pragma unroll
    for (int s = 0; s < 2; s++)
        #pragma unroll
        for (int ks = 0; ks < 2; ks++) {
            int col = s * 64 + ks * 32 + lq * 8;
            int by = (l15 * 256 + col * 2) ^ ((l15 & 7) << 4);
            af[s][ks] = *(const bf16x8*)((const char*)hid_s + by);
        }

    const unsigned short* W2lo = W2p + (size_t)lo * (CH * 3 * OD);
    const unsigned short* W2hi = W2p + (size_t)hi * (CH * 3 * OD);
    const float* b2lo = b2 + (size_t)lo * 3072;
    const float* b2hi = b2 + (size_t)hi * 3072;

    int   tok_r[4];
    float twx[4], twy[4];
    #pragma unroll
    for (int i = 0; i < 4; i++) {
        int trow = lq * 4 + i;
        tok_r[i] = toks[trow];
        float2 t2 = tw[trow];
        twx[i] = t2.x; twy[i] = t2.y;
    }

    for (int ot = 0; ot < 8; ot++) {
        int o = w * 128 + ot * 16 + l15;
        float xo[4], vo[4];
        #pragma unroll
        for (int i = 0; i < 4; i++) {
            size_t off = (size_t)tok_r[i] * OD + o;
            xo[i] = x[off];
            vo[i] = v[off];
        }
        float muo = mu[o];
        float accVN[4] = {0.f,0.f,0.f,0.f};
        float accGV[4] = {0.f,0.f,0.f,0.f};

        #pragma unroll
        for (int s = 0; s < 2; s++) {
            const unsigned short* W2e = s ? W2hi : W2lo;
            const float* b2e = s ? b2hi : b2lo;
            f32x4 aA = {0.f,0.f,0.f,0.f};
            f32x4 aB = {0.f,0.f,0.f,0.f};
            f32x4 aG = {0.f,0.f,0.f,0.f};
            #pragma unroll
            for (int ks = 0; ks < 2; ks++) {
                int kb = ks * 4 + lq;
                bf16x8 wA = *(const bf16x8*)(W2e + ((size_t)kb * 3072 + o) * 8);
                bf16x8 wB = *(const bf16x8*)(W2e + ((size_t)kb * 3072 + OD + o) * 8);
                bf16x8 wG = *(const bf16x8*)(W2e + ((size_t)kb * 3072 + 2 * OD + o) * 8);
                aA = __builtin_amdgcn_mfma_f32_16x16x32_bf16(af[s][ks], wA, aA, 0, 0, 0);
                aB = __builtin_amdgcn_mfma_f32_16x16x32_bf16(af[s][ks], wB, aB, 0, 0, 0);
                aG = __builtin_amdgcn_mfma_f32_16x16x32_bf16(af[s][ks], wG, aG, 0, 0, 0);
            }
            float ba = b2e[o], bb = b2e[OD + o], bg = b2e[2 * OD + o];
            #pragma unroll
            for (int i = 0; i < 4; i++) {
                float za = aA[i] + ba;
                float zb = aB[i] + bb;
                float zg = aG[i] + bg;
                float alpha = fsigmoid(za);
                float beta  = fsoftplus(zb);
                float gate  = fsigmoid(zg);
                float ws = s ? twy[i] : twx[i];
                float vn_s = alpha * vo[i] - beta * (xo[i] - muo);
                accVN[i] += ws * vn_s;
                accGV[i] += ws * gate * vn_s;
            }
        }
        #pragma unroll
        for (int i = 0; i < 4; i++) {
            if (lq * 4 + i < nt) {
                size_t off = (size_t)tok_r[i] * OD + o;
                out[off]          = xo[i] + 0.1f * accGV[i];
                out[OFF_VN + off] = accVN[i];
            }
        }
    }
}

extern "C" void kernel_launch(void* const* d_in, const int* in_sizes, int n_in,
                              void* d_out, int out_size, void* d_ws, size_t ws_size,
                              hipStream_t stream)
{
    (void)in_sizes; (void)n_in; (void)out_size; (void)ws_size;
    const float* h  = (const float*)d_in[0];
    const float* x  = (const float*)d_in[1];
    const float* v  = (const float*)d_in[2];
    const float* rw = (const float*)d_in[3];
    const float* rb = (const float*)d_in[4];
    const float* mu = (const float*)d_in[5];
    const float* W1 = (const float*)d_in[6];
    const float* b1 = (const float*)d_in[7];
    const float* W2 = (const float*)d_in[8];
    const float* b2 = (const float*)d_in[9];
    float* out = (float*)d_out;

    char* ws = (char*)d_ws;
    int*    pcnt  = (int*)(ws + WS_PCNT);
    int*    total = (int*)(ws + WS_TOTAL);
    int*    table = (int*)(ws + WS_TABLE);
    int*    plist = (int*)(ws + WS_PLIST);
    float2* pwts  = (float2*)(ws + WS_PWTS);
    unsigned short* W1p  = (unsigned short*)(ws + WS_W1P);
    unsigned short* W2p  = (unsigned short*)(ws + WS_W2P);
    unsigned short* ctxb = (unsigned short*)(ws + WS_CTXB);

    hipMemsetAsync(pcnt, 0, 64 * sizeof(int), stream);

    pre_kernel<<<3840, 256, 0, stream>>>(h, x, v, rw, rb, W1, W2,
                                         W1p, W2p, ctxb, out,
                                         pcnt, plist, pwts);
    prefix_kernel<<<1, 64, 0, stream>>>(pcnt, table, total);
    moe_kernel<<<576, 512, 0, stream>>>(x, v, mu, b1, b2, W1p, W2p, ctxb,
                                        pcnt, table, total, plist, pwts, out);
}

// Round 19
// 186.472 us; speedup vs baseline: 1.2166x; 1.0571x over previous
//
#include <hip/hip_runtime.h>
#include <math.h>

#define NTOK 8192
#define HD   2048
#define OD   1024
#define NE   8
#define CTXD 4096
#define CH   64

typedef short bf16x8 __attribute__((ext_vector_type(8)));
typedef float f32x4  __attribute__((ext_vector_type(4)));

static const size_t OFF_VN = (size_t)NTOK * OD;                 // v_next
static const size_t OFF_RP = 2 * (size_t)NTOK * OD;             // router_probs
static const size_t OFF_TI = OFF_RP + (size_t)NTOK * NE;        // top_k_idx
static const size_t OFF_TP = OFF_TI + (size_t)NTOK * 2;         // top_k_probs

// ---- ws byte offsets (identical to r13/r18 footprint) ----
#define WS_PCNT   0
#define WS_TOTAL  256
#define WS_TABLE  512
#define WS_PLIST  8192
#define WS_PWTS   (8192 + 64*NTOK*4)
#define WS_W1P    (WS_PWTS + 64*NTOK*8)
#define WS_W2P    (WS_W1P + NE*CTXD*CH*2)
#define WS_CTXB   (WS_W2P + NE*CH*3*OD*2)

__device__ __forceinline__ unsigned bfpack2(float a, float b) {
    unsigned ua = __float_as_uint(a), ub = __float_as_uint(b);
    ua = (ua + 0x7FFFu + ((ua >> 16) & 1u)) >> 16;
    ub = (ub + 0x7FFFu + ((ub >> 16) & 1u)) >> 16;
    return ua | (ub << 16);
}
__device__ __forceinline__ unsigned short bf1(float a) {
    unsigned ua = __float_as_uint(a);
    return (unsigned short)((ua + 0x7FFFu + ((ua >> 16) & 1u)) >> 16);
}
__device__ __forceinline__ float fsigmoid(float z) {
    return __fdividef(1.f, 1.f + __expf(-z));
}
__device__ __forceinline__ float fsoftplus(float z) {
    return fmaxf(z, 0.f) + __logf(1.f + __expf(-fabsf(z)));
}
__device__ __forceinline__ void gl_lds16(const void* g, void* l) {
    __builtin_amdgcn_global_load_lds(
        (const __attribute__((address_space(1))) void*)g,
        (__attribute__((address_space(3))) void*)l, 16, 0, 0);
}

// ---------------- fused pre-pass (r18 layout):
// blocks [0,1024): W1 -> W1p [8][512][64][8]
// blocks [1024,1792): W2 -> W2p [8][8][3072][8]
// blocks [1792,3840): one wave per token: ctx->bf16 + coalesced-row router
__global__ __launch_bounds__(256) void pre_kernel(
    const float* __restrict__ h, const float* __restrict__ x,
    const float* __restrict__ v, const float* __restrict__ rw,
    const float* __restrict__ rb,
    const float* __restrict__ W1, const float* __restrict__ W2,
    unsigned short* __restrict__ W1p, unsigned short* __restrict__ W2p,
    unsigned short* __restrict__ ctxb,
    float* __restrict__ out,
    int* __restrict__ pcnt, int* __restrict__ plist, float2* __restrict__ pwts)
{
    int bb = blockIdx.x;
    int tid = threadIdx.x;
    if (bb < 1024) {
        int flat = bb * 256 + tid;
        int e = flat >> 15, rem = flat & 32767;
        int kb = rem >> 6, c = rem & 63;
        const float* src = W1 + (size_t)e * CTXD * CH + (size_t)kb * 8 * CH + c;
        uint4 o;
        o.x = bfpack2(src[0 * 64], src[1 * 64]);
        o.y = bfpack2(src[2 * 64], src[3 * 64]);
        o.z = bfpack2(src[4 * 64], src[5 * 64]);
        o.w = bfpack2(src[6 * 64], src[7 * 64]);
        *(uint4*)(W1p + (size_t)flat * 8) = o;
        return;
    }
    if (bb < 1792) {
        int flat = (bb - 1024) * 256 + tid;
        int e = flat / 24576, rem = flat - e * 24576;
        int kb = rem / 3072, c = rem - kb * 3072;
        const float* src = W2 + ((size_t)e * CH + kb * 8) * (3 * OD) + c;
        uint4 o;
        o.x = bfpack2(src[0 * 3072], src[1 * 3072]);
        o.y = bfpack2(src[2 * 3072], src[3 * 3072]);
        o.z = bfpack2(src[4 * 3072], src[5 * 3072]);
        o.w = bfpack2(src[6 * 3072], src[7 * 3072]);
        *(uint4*)(W2p + (size_t)flat * 8) = o;
        return;
    }
    // ---- ctx -> bf16 + router: one wave per token ----
    int lane = tid & 63;
    int wv   = tid >> 6;
    int t    = (bb - 1792) * 4 + wv;
    const float* hb = h + (size_t)t * HD;
    const float* xb = x + (size_t)t * OD;
    const float* vb = v + (size_t)t * OD;
    unsigned short* cb = ctxb + (size_t)t * CTXD;

    // ctx pack: 16 x float4 per lane, coalesced
    #pragma unroll
    for (int i = 0; i < 16; i++) {
        int col = i * 256 + lane * 4;
        float4 f;
        if (i < 8)       f = *(const float4*)(hb + col);
        else if (i < 12) f = *(const float4*)(xb + (col - HD));
        else             f = *(const float4*)(vb + (col - HD - OD));
        uint2 pk = make_uint2(bfpack2(f.x, f.y), bfpack2(f.z, f.w));
        *(uint2*)(cb + col) = pk;
    }

    // router: lane owns rows rr*64+lane; rw row loads at 32B lane-stride
    float r0=0.f,r1=0.f,r2=0.f,r3=0.f,r4=0.f,r5=0.f,r6=0.f,r7=0.f;
    #pragma unroll 8
    for (int rr = 0; rr < 32; rr++) {
        int row = rr * 64 + lane;
        float hv = hb[row];
        const float4* rwp = (const float4*)(rw + (size_t)row * 8);
        float4 wA = rwp[0], wB = rwp[1];
        r0 = fmaf(hv, wA.x, r0); r1 = fmaf(hv, wA.y, r1);
        r2 = fmaf(hv, wA.z, r2); r3 = fmaf(hv, wA.w, r3);
        r4 = fmaf(hv, wB.x, r4); r5 = fmaf(hv, wB.y, r5);
        r6 = fmaf(hv, wB.z, r6); r7 = fmaf(hv, wB.w, r7);
    }
    #pragma unroll
    for (int off = 32; off >= 1; off >>= 1) {
        r0 += __shfl_xor(r0, off); r1 += __shfl_xor(r1, off);
        r2 += __shfl_xor(r2, off); r3 += __shfl_xor(r3, off);
        r4 += __shfl_xor(r4, off); r5 += __shfl_xor(r5, off);
        r6 += __shfl_xor(r6, off); r7 += __shfl_xor(r7, off);
    }
    if (lane == 0) {
        float lg[8] = {r0+rb[0], r1+rb[1], r2+rb[2], r3+rb[3],
                       r4+rb[4], r5+rb[5], r6+rb[6], r7+rb[7]};
        float m = lg[0];
        #pragma unroll
        for (int e2 = 1; e2 < 8; e2++) m = fmaxf(m, lg[e2]);
        float p[8]; float s = 0.f;
        #pragma unroll
        for (int e2 = 0; e2 < 8; e2++) { p[e2] = expf(lg[e2] - m); s += p[e2]; }
        float inv = 1.f / s;
        #pragma unroll
        for (int e2 = 0; e2 < 8; e2++) {
            p[e2] *= inv;
            out[OFF_RP + (size_t)t * 8 + e2] = p[e2];
        }
        int e0 = 0;
        #pragma unroll
        for (int e2 = 1; e2 < 8; e2++) if (p[e2] > p[e0]) e0 = e2;
        int e1 = (e0 == 0) ? 1 : 0;
        #pragma unroll
        for (int e2 = 0; e2 < 8; e2++) {
            if (e2 == e0) continue;
            if (p[e2] > p[e1]) e1 = e2;
        }
        float s2 = p[e0] + p[e1];
        float w0 = p[e0] / s2, w1 = p[e1] / s2;
        out[OFF_TI + (size_t)t*2 + 0] = (float)e0;
        out[OFF_TI + (size_t)t*2 + 1] = (float)e1;
        out[OFF_TP + (size_t)t*2 + 0] = w0;
        out[OFF_TP + (size_t)t*2 + 1] = w1;
        int lo = min(e0, e1), hi = max(e0, e1);
        float wlo = (e0 < e1) ? w0 : w1;
        float whi = (e0 < e1) ? w1 : w0;
        int pid = lo * 8 + hi;
        int pos = atomicAdd(&pcnt[pid], 1);
        plist[pid * NTOK + pos] = t;
        pwts[pid * NTOK + pos] = make_float2(wlo, whi);
    }
}

// ---------------- prefix: pid counts -> dense 16-token tile table
__global__ void prefix_kernel(const int* __restrict__ pcnt,
                              int* __restrict__ table, int* __restrict__ total) {
    int tid = threadIdx.x;
    int cnt = pcnt[tid];
    int tiles = (cnt + 15) >> 4;
    int incl = tiles;
    #pragma unroll
    for (int off = 1; off < 64; off <<= 1) {
        int v = __shfl_up(incl, off);
        if (tid >= off) incl += v;
    }
    int base = incl - tiles;
    for (int i = 0; i < tiles; i++) table[base + i] = tid | (i << 6);
    if (tid == 63) *total = incl;
}

// ---------------- MoE: depth-2 counted-vmcnt pipelined stage-1 (T3/T4)
__global__ __launch_bounds__(512) void moe_kernel(
    const float* __restrict__ x, const float* __restrict__ v,
    const float* __restrict__ mu,
    const float* __restrict__ b1, const float* __restrict__ b2,
    const unsigned short* __restrict__ W1p, const unsigned short* __restrict__ W2p,
    const unsigned short* __restrict__ ctxb,
    const int* __restrict__ pcnt, const int* __restrict__ table,
    const int* __restrict__ total, const int* __restrict__ plist,
    const float2* __restrict__ pwts, float* __restrict__ out)
{
    __shared__ unsigned short abuf[3][8192];     // triple-buffer 16tok x 512c (3x16KB)
    __shared__ unsigned short hid_s[16 * 128];   // swizzled bf16 [16 tok][2*64]  4 KB
    __shared__ int    toks[16];
    __shared__ float2 tw[16];

    int bid = (blockIdx.x & 7) * 72 + (blockIdx.x >> 3);   // XCD-chunked, 576=8*72
    if (bid >= *total) return;
    int entry = table[bid];
    int pid = entry & 63;
    int start = (entry >> 6) * 16;
    int lo = pid >> 3, hi = pid & 7;
    int cnt = pcnt[pid];
    int nt = cnt - start; if (nt > 16) nt = 16;

    int tid = threadIdx.x;
    if (tid < 16) {
        int idx = start + (tid < nt ? tid : 0);
        toks[tid] = plist[pid * NTOK + idx];
        tw[tid]   = pwts[pid * NTOK + idx];
    }
    __syncthreads();

    int lane = tid & 63, w = tid >> 6;           // 8 waves
    int l15 = lane & 15, lq = lane >> 4;

    // stage-1 wave roles: (expert slot, col-group); full-K accumulation
    int s1s = w >> 2;                            // 0 = lo, 1 = hi
    int cg  = w & 3;                             // 16-col group within expert's 64
    int myE = s1s ? hi : lo;
    int colw = cg * 16 + l15;
    const unsigned short* W1e = W1p + (size_t)myE * (CTXD * CH);

    // staging: per chunk (512 cols), wave w stages token rows 2w, 2w+1
    int wv2 = w * 2;

#define STAGE(KC, BUF) do {                                                    \
        _Pragma("unroll")                                                      \
        for (int j = 0; j < 2; j++) {                                          \
            int r_ = wv2 + j;                                                  \
            int tok_ = toks[r_];                                               \
            int soff_ = ((lane * 16) ^ ((r_ & 7) << 4)) >> 1;                  \
            const unsigned short* gs_ = ctxb + (size_t)tok_ * CTXD             \
                                        + (KC) * 512 + soff_;                  \
            gl_lds16(gs_, (char*)abuf[BUF] + w * 2048 + j * 1024);             \
        }                                                                      \
    } while (0)

#define COMPUTE(KC, BUF) do {                                                  \
        _Pragma("unroll")                                                      \
        for (int ks = 0; ks < 16; ks++) {                                      \
            int phys = (ks * 64 + lq * 16) ^ ((l15 & 7) << 4);                 \
            bf16x8 a = *(const bf16x8*)((const char*)abuf[BUF]                 \
                                        + l15 * 1024 + phys);                  \
            int kb = (KC) * 64 + ks * 4 + lq;                                  \
            bf16x8 b = *(const bf16x8*)(W1e + ((size_t)kb * 64 + colw) * 8);   \
            acc = __builtin_amdgcn_mfma_f32_16x16x32_bf16(a, b, acc, 0, 0, 0); \
        }                                                                      \
    } while (0)

// one chunk: prefetch kc+2, counted-vmcnt wait for kc, compute, release barrier
#define CHUNK(KC, VM) do {                                                     \
        if ((KC) + 2 < 8) STAGE((KC) + 2, ((KC) + 2) % 3);                     \
        asm volatile("s_waitcnt vmcnt(" #VM ")" ::: "memory");                 \
        __builtin_amdgcn_s_barrier();                                          \
        COMPUTE(KC, (KC) % 3);                                                 \
        asm volatile("" ::: "memory");                                         \
        __builtin_amdgcn_s_barrier();                                          \
    } while (0)

    f32x4 acc = {0.f, 0.f, 0.f, 0.f};

    STAGE(0, 0);
    STAGE(1, 1);
    CHUNK(0, 4);  CHUNK(1, 4);  CHUNK(2, 4);  CHUNK(3, 4);
    CHUNK(4, 4);  CHUNK(5, 4);  CHUNK(6, 2);  CHUNK(7, 0);
#undef STAGE
#undef COMPUTE
#undef CHUNK

    // relu + bias -> hid LDS (bf16, swizzled). C layout: col=l15, row=lq*4+i
    {
        float b1v = b1[myE * CH + colw];
        int colh = s1s * 64 + colw;
        #pragma unroll
        for (int i = 0; i < 4; i++) {
            int r0 = lq * 4 + i;
            float hv = acc[i] + b1v; hv = hv > 0.f ? hv : 0.f;
            int by = (r0 * 256 + colh * 2) ^ ((r0 & 7) << 4);
            *(unsigned short*)((char*)hid_s + by) = bf1(hv);
        }
    }
    __syncthreads();

    // ---- stage 2: wave w owns o-band [w*128, w*128+128)
    bf16x8 af[2][2];
    #pragma unroll
    for (int s = 0; s < 2; s++)
        #pragma unroll
        for (int ks = 0; ks < 2; ks++) {
            int col = s * 64 + ks * 32 + lq * 8;
            int by = (l15 * 256 + col * 2) ^ ((l15 & 7) << 4);
            af[s][ks] = *(const bf16x8*)((const char*)hid_s + by);
        }

    const unsigned short* W2lo = W2p + (size_t)lo * (CH * 3 * OD);
    const unsigned short* W2hi = W2p + (size_t)hi * (CH * 3 * OD);
    const float* b2lo = b2 + (size_t)lo * 3072;
    const float* b2hi = b2 + (size_t)hi * 3072;

    int   tok_r[4];
    float twx[4], twy[4];
    #pragma unroll
    for (int i = 0; i < 4; i++) {
        int trow = lq * 4 + i;
        tok_r[i] = toks[trow];
        float2 t2 = tw[trow];
        twx[i] = t2.x; twy[i] = t2.y;
    }

    for (int ot = 0; ot < 8; ot++) {
        int o = w * 128 + ot * 16 + l15;
        float xo[4], vo[4];
        #pragma unroll
        for (int i = 0; i < 4; i++) {
            size_t off = (size_t)tok_r[i] * OD + o;
            xo[i] = x[off];
            vo[i] = v[off];
        }
        float muo = mu[o];
        float accVN[4] = {0.f,0.f,0.f,0.f};
        float accGV[4] = {0.f,0.f,0.f,0.f};

        #pragma unroll
        for (int s = 0; s < 2; s++) {
            const unsigned short* W2e = s ? W2hi : W2lo;
            const float* b2e = s ? b2hi : b2lo;
            f32x4 aA = {0.f,0.f,0.f,0.f};
            f32x4 aB = {0.f,0.f,0.f,0.f};
            f32x4 aG = {0.f,0.f,0.f,0.f};
            #pragma unroll
            for (int ks = 0; ks < 2; ks++) {
                int kb = ks * 4 + lq;
                bf16x8 wA = *(const bf16x8*)(W2e + ((size_t)kb * 3072 + o) * 8);
                bf16x8 wB = *(const bf16x8*)(W2e + ((size_t)kb * 3072 + OD + o) * 8);
                bf16x8 wG = *(const bf16x8*)(W2e + ((size_t)kb * 3072 + 2 * OD + o) * 8);
                aA = __builtin_amdgcn_mfma_f32_16x16x32_bf16(af[s][ks], wA, aA, 0, 0, 0);
                aB = __builtin_amdgcn_mfma_f32_16x16x32_bf16(af[s][ks], wB, aB, 0, 0, 0);
                aG = __builtin_amdgcn_mfma_f32_16x16x32_bf16(af[s][ks], wG, aG, 0, 0, 0);
            }
            float ba = b2e[o], bb = b2e[OD + o], bg = b2e[2 * OD + o];
            #pragma unroll
            for (int i = 0; i < 4; i++) {
                float za = aA[i] + ba;
                float zb = aB[i] + bb;
                float zg = aG[i] + bg;
                float alpha = fsigmoid(za);
                float beta  = fsoftplus(zb);
                float gate  = fsigmoid(zg);
                float ws = s ? twy[i] : twx[i];
                float vn_s = alpha * vo[i] - beta * (xo[i] - muo);
                accVN[i] += ws * vn_s;
                accGV[i] += ws * gate * vn_s;
            }
        }
        #pragma unroll
        for (int i = 0; i < 4; i++) {
            if (lq * 4 + i < nt) {
                size_t off = (size_t)tok_r[i] * OD + o;
                out[off]          = xo[i] + 0.1f * accGV[i];
                out[OFF_VN + off] = accVN[i];
            }
        }
    }
}

extern "C" void kernel_launch(void* const* d_in, const int* in_sizes, int n_in,
                              void* d_out, int out_size, void* d_ws, size_t ws_size,
                              hipStream_t stream)
{
    (void)in_sizes; (void)n_in; (void)out_size; (void)ws_size;
    const float* h  = (const float*)d_in[0];
    const float* x  = (const float*)d_in[1];
    const float* v  = (const float*)d_in[2];
    const float* rw = (const float*)d_in[3];
    const float* rb = (const float*)d_in[4];
    const float* mu = (const float*)d_in[5];
    const float* W1 = (const float*)d_in[6];
    const float* b1 = (const float*)d_in[7];
    const float* W2 = (const float*)d_in[8];
    const float* b2 = (const float*)d_in[9];
    float* out = (float*)d_out;

    char* ws = (char*)d_ws;
    int*    pcnt  = (int*)(ws + WS_PCNT);
    int*    total = (int*)(ws + WS_TOTAL);
    int*    table = (int*)(ws + WS_TABLE);
    int*    plist = (int*)(ws + WS_PLIST);
    float2* pwts  = (float2*)(ws + WS_PWTS);
    unsigned short* W1p  = (unsigned short*)(ws + WS_W1P);
    unsigned short* W2p  = (unsigned short*)(ws + WS_W2P);
    unsigned short* ctxb = (unsigned short*)(ws + WS_CTXB);

    hipMemsetAsync(pcnt, 0, 64 * sizeof(int), stream);

    pre_kernel<<<3840, 256, 0, stream>>>(h, x, v, rw, rb, W1, W2,
                                         W1p, W2p, ctxb, out,
                                         pcnt, plist, pwts);
    prefix_kernel<<<1, 64, 0, stream>>>(pcnt, table, total);
    moe_kernel<<<576, 512, 0, stream>>>(x, v, mu, b1, b2, W1p, W2p, ctxb,
                                        pcnt, table, total, plist, pwts, out);
}

// Round 20
// 186.334 us; speedup vs baseline: 1.2175x; 1.0007x over previous
//
#include <hip/hip_runtime.h>
#include <math.h>

#define NTOK 8192
#define HD   2048
#define OD   1024
#define NE   8
#define CTXD 4096
#define CH   64

typedef short bf16x8 __attribute__((ext_vector_type(8)));
typedef float f32x4  __attribute__((ext_vector_type(4)));

static const size_t OFF_VN = (size_t)NTOK * OD;                 // v_next
static const size_t OFF_RP = 2 * (size_t)NTOK * OD;             // router_probs
static const size_t OFF_TI = OFF_RP + (size_t)NTOK * NE;        // top_k_idx
static const size_t OFF_TP = OFF_TI + (size_t)NTOK * 2;         // top_k_probs

// ---- ws byte offsets (identical to r13/r18 footprint) ----
#define WS_PCNT   0
#define WS_TOTAL  256
#define WS_TABLE  512
#define WS_PLIST  8192
#define WS_PWTS   (8192 + 64*NTOK*4)
#define WS_W1P    (WS_PWTS + 64*NTOK*8)
#define WS_W2P    (WS_W1P + NE*CTXD*CH*2)
#define WS_CTXB   (WS_W2P + NE*CH*3*OD*2)

__device__ __forceinline__ unsigned bfpack2(float a, float b) {
    unsigned ua = __float_as_uint(a), ub = __float_as_uint(b);
    ua = (ua + 0x7FFFu + ((ua >> 16) & 1u)) >> 16;
    ub = (ub + 0x7FFFu + ((ub >> 16) & 1u)) >> 16;
    return ua | (ub << 16);
}
__device__ __forceinline__ unsigned short bf1(float a) {
    unsigned ua = __float_as_uint(a);
    return (unsigned short)((ua + 0x7FFFu + ((ua >> 16) & 1u)) >> 16);
}
__device__ __forceinline__ float fsigmoid(float z) {
    return __fdividef(1.f, 1.f + __expf(-z));
}
__device__ __forceinline__ float fsoftplus(float z) {
    return fmaxf(z, 0.f) + __logf(1.f + __expf(-fabsf(z)));
}
__device__ __forceinline__ void gl_lds16(const void* g, void* l) {
    __builtin_amdgcn_global_load_lds(
        (const __attribute__((address_space(1))) void*)g,
        (__attribute__((address_space(3))) void*)l, 16, 0, 0);
}

// ---------------- fused pre-pass (r18 layout):
// blocks [0,1024): W1 -> W1p [8][512][64][8]
// blocks [1024,1792): W2 -> W2p [8][8][3072][8]
// blocks [1792,3840): one wave per token: ctx->bf16 (16B stores) + router
__global__ __launch_bounds__(256) void pre_kernel(
    const float* __restrict__ h, const float* __restrict__ x,
    const float* __restrict__ v, const float* __restrict__ rw,
    const float* __restrict__ rb,
    const float* __restrict__ W1, const float* __restrict__ W2,
    unsigned short* __restrict__ W1p, unsigned short* __restrict__ W2p,
    unsigned short* __restrict__ ctxb,
    float* __restrict__ out,
    int* __restrict__ pcnt, int* __restrict__ plist, float2* __restrict__ pwts)
{
    int bb = blockIdx.x;
    int tid = threadIdx.x;
    if (bb < 1024) {
        int flat = bb * 256 + tid;
        int e = flat >> 15, rem = flat & 32767;
        int kb = rem >> 6, c = rem & 63;
        const float* src = W1 + (size_t)e * CTXD * CH + (size_t)kb * 8 * CH + c;
        uint4 o;
        o.x = bfpack2(src[0 * 64], src[1 * 64]);
        o.y = bfpack2(src[2 * 64], src[3 * 64]);
        o.z = bfpack2(src[4 * 64], src[5 * 64]);
        o.w = bfpack2(src[6 * 64], src[7 * 64]);
        *(uint4*)(W1p + (size_t)flat * 8) = o;
        return;
    }
    if (bb < 1792) {
        int flat = (bb - 1024) * 256 + tid;
        int e = flat / 24576, rem = flat - e * 24576;
        int kb = rem / 3072, c = rem - kb * 3072;
        const float* src = W2 + ((size_t)e * CH + kb * 8) * (3 * OD) + c;
        uint4 o;
        o.x = bfpack2(src[0 * 3072], src[1 * 3072]);
        o.y = bfpack2(src[2 * 3072], src[3 * 3072]);
        o.z = bfpack2(src[4 * 3072], src[5 * 3072]);
        o.w = bfpack2(src[6 * 3072], src[7 * 3072]);
        *(uint4*)(W2p + (size_t)flat * 8) = o;
        return;
    }
    // ---- ctx -> bf16 + router: one wave per token ----
    int lane = tid & 63;
    int wv   = tid >> 6;
    int t    = (bb - 1792) * 4 + wv;
    const float* hb = h + (size_t)t * HD;
    const float* xb = x + (size_t)t * OD;
    const float* vb = v + (size_t)t * OD;
    unsigned short* cb = ctxb + (size_t)t * CTXD;

    // ctx pack: lane owns 8 contiguous floats/iter -> one 16B store (full rate)
    #pragma unroll
    for (int i = 0; i < 8; i++) {
        int col = i * 512 + lane * 8;
        const float* s;
        if (i < 4)      s = hb + col;
        else if (i < 6) s = xb + (col - HD);
        else            s = vb + (col - HD - OD);
        float4 f0 = ((const float4*)s)[0];
        float4 f1 = ((const float4*)s)[1];
        uint4 pk;
        pk.x = bfpack2(f0.x, f0.y); pk.y = bfpack2(f0.z, f0.w);
        pk.z = bfpack2(f1.x, f1.y); pk.w = bfpack2(f1.z, f1.w);
        *(uint4*)(cb + col) = pk;
    }

    // router: lane owns rows rr*64+lane; rw row loads at 32B lane-stride
    float r0=0.f,r1=0.f,r2=0.f,r3=0.f,r4=0.f,r5=0.f,r6=0.f,r7=0.f;
    #pragma unroll 8
    for (int rr = 0; rr < 32; rr++) {
        int row = rr * 64 + lane;
        float hv = hb[row];                      // L1-hot (just packed)
        const float4* rwp = (const float4*)(rw + (size_t)row * 8);
        float4 wA = rwp[0], wB = rwp[1];
        r0 = fmaf(hv, wA.x, r0); r1 = fmaf(hv, wA.y, r1);
        r2 = fmaf(hv, wA.z, r2); r3 = fmaf(hv, wA.w, r3);
        r4 = fmaf(hv, wB.x, r4); r5 = fmaf(hv, wB.y, r5);
        r6 = fmaf(hv, wB.z, r6); r7 = fmaf(hv, wB.w, r7);
    }
    #pragma unroll
    for (int off = 32; off >= 1; off >>= 1) {
        r0 += __shfl_xor(r0, off); r1 += __shfl_xor(r1, off);
        r2 += __shfl_xor(r2, off); r3 += __shfl_xor(r3, off);
        r4 += __shfl_xor(r4, off); r5 += __shfl_xor(r5, off);
        r6 += __shfl_xor(r6, off); r7 += __shfl_xor(r7, off);
    }
    if (lane == 0) {
        float lg[8] = {r0+rb[0], r1+rb[1], r2+rb[2], r3+rb[3],
                       r4+rb[4], r5+rb[5], r6+rb[6], r7+rb[7]};
        float m = lg[0];
        #pragma unroll
        for (int e2 = 1; e2 < 8; e2++) m = fmaxf(m, lg[e2]);
        float p[8]; float s = 0.f;
        #pragma unroll
        for (int e2 = 0; e2 < 8; e2++) { p[e2] = expf(lg[e2] - m); s += p[e2]; }
        float inv = 1.f / s;
        #pragma unroll
        for (int e2 = 0; e2 < 8; e2++) {
            p[e2] *= inv;
            out[OFF_RP + (size_t)t * 8 + e2] = p[e2];
        }
        int e0 = 0;
        #pragma unroll
        for (int e2 = 1; e2 < 8; e2++) if (p[e2] > p[e0]) e0 = e2;
        int e1 = (e0 == 0) ? 1 : 0;
        #pragma unroll
        for (int e2 = 0; e2 < 8; e2++) {
            if (e2 == e0) continue;
            if (p[e2] > p[e1]) e1 = e2;
        }
        float s2 = p[e0] + p[e1];
        float w0 = p[e0] / s2, w1 = p[e1] / s2;
        out[OFF_TI + (size_t)t*2 + 0] = (float)e0;
        out[OFF_TI + (size_t)t*2 + 1] = (float)e1;
        out[OFF_TP + (size_t)t*2 + 0] = w0;
        out[OFF_TP + (size_t)t*2 + 1] = w1;
        int lo = min(e0, e1), hi = max(e0, e1);
        float wlo = (e0 < e1) ? w0 : w1;
        float whi = (e0 < e1) ? w1 : w0;
        int pid = lo * 8 + hi;
        int pos = atomicAdd(&pcnt[pid], 1);
        plist[pid * NTOK + pos] = t;
        pwts[pid * NTOK + pos] = make_float2(wlo, whi);
    }
}

// ---------------- prefix: pid counts -> dense 16-token tile table
__global__ void prefix_kernel(const int* __restrict__ pcnt,
                              int* __restrict__ table, int* __restrict__ total) {
    int tid = threadIdx.x;
    int cnt = pcnt[tid];
    int tiles = (cnt + 15) >> 4;
    int incl = tiles;
    #pragma unroll
    for (int off = 1; off < 64; off <<= 1) {
        int v = __shfl_up(incl, off);
        if (tid >= off) incl += v;
    }
    int base = incl - tiles;
    for (int i = 0; i < tiles; i++) table[base + i] = tid | (i << 6);
    if (tid == 63) *total = incl;
}

// ---------------- MoE: depth-2 counted-vmcnt pipelined stage-1 (T3/T4)
__global__ __launch_bounds__(512) void moe_kernel(
    const float* __restrict__ x, const float* __restrict__ v,
    const float* __restrict__ mu,
    const float* __restrict__ b1, const float* __restrict__ b2,
    const unsigned short* __restrict__ W1p, const unsigned short* __restrict__ W2p,
    const unsigned short* __restrict__ ctxb,
    const int* __restrict__ pcnt, const int* __restrict__ table,
    const int* __restrict__ total, const int* __restrict__ plist,
    const float2* __restrict__ pwts, float* __restrict__ out)
{
    __shared__ unsigned short abuf[3][8192];     // triple-buffer 16tok x 512c (3x16KB)
    __shared__ unsigned short hid_s[16 * 128];   // swizzled bf16 [16 tok][2*64]  4 KB
    __shared__ int    toks[16];
    __shared__ float2 tw[16];

    int bid = (blockIdx.x & 7) * 72 + (blockIdx.x >> 3);   // XCD-chunked, 576=8*72
    if (bid >= *total) return;
    int entry = table[bid];
    int pid = entry & 63;
    int start = (entry >> 6) * 16;
    int lo = pid >> 3, hi = pid & 7;
    int cnt = pcnt[pid];
    int nt = cnt - start; if (nt > 16) nt = 16;

    int tid = threadIdx.x;
    if (tid < 16) {
        int idx = start + (tid < nt ? tid : 0);
        toks[tid] = plist[pid * NTOK + idx];
        tw[tid]   = pwts[pid * NTOK + idx];
    }
    __syncthreads();

    int lane = tid & 63, w = tid >> 6;           // 8 waves
    int l15 = lane & 15, lq = lane >> 4;

    // stage-1 wave roles: (expert slot, col-group); full-K accumulation
    int s1s = w >> 2;                            // 0 = lo, 1 = hi
    int cg  = w & 3;                             // 16-col group within expert's 64
    int myE = s1s ? hi : lo;
    int colw = cg * 16 + l15;
    const unsigned short* W1e = W1p + (size_t)myE * (CTXD * CH);

    // staging: per chunk (512 cols), wave w stages token rows 2w, 2w+1
    int wv2 = w * 2;

#define STAGE(KC, BUF) do {                                                    \
        _Pragma("unroll")                                                      \
        for (int j = 0; j < 2; j++) {                                          \
            int r_ = wv2 + j;                                                  \
            int tok_ = toks[r_];                                               \
            int soff_ = ((lane * 16) ^ ((r_ & 7) << 4)) >> 1;                  \
            const unsigned short* gs_ = ctxb + (size_t)tok_ * CTXD             \
                                        + (KC) * 512 + soff_;                  \
            gl_lds16(gs_, (char*)abuf[BUF] + w * 2048 + j * 1024);             \
        }                                                                      \
    } while (0)

#define COMPUTE(KC, BUF) do {                                                  \
        _Pragma("unroll")                                                      \
        for (int ks = 0; ks < 16; ks++) {                                      \
            int phys = (ks * 64 + lq * 16) ^ ((l15 & 7) << 4);                 \
            bf16x8 a = *(const bf16x8*)((const char*)abuf[BUF]                 \
                                        + l15 * 1024 + phys);                  \
            int kb = (KC) * 64 + ks * 4 + lq;                                  \
            bf16x8 b = *(const bf16x8*)(W1e + ((size_t)kb * 64 + colw) * 8);   \
            acc = __builtin_amdgcn_mfma_f32_16x16x32_bf16(a, b, acc, 0, 0, 0); \
        }                                                                      \
    } while (0)

// one chunk: prefetch kc+2, counted-vmcnt wait for kc, compute, release barrier
#define CHUNK(KC, VM) do {                                                     \
        if ((KC) + 2 < 8) STAGE((KC) + 2, ((KC) + 2) % 3);                     \
        asm volatile("s_waitcnt vmcnt(" #VM ")" ::: "memory");                 \
        __builtin_amdgcn_s_barrier();                                          \
        COMPUTE(KC, (KC) % 3);                                                 \
        asm volatile("" ::: "memory");                                         \
        __builtin_amdgcn_s_barrier();                                          \
    } while (0)

    f32x4 acc = {0.f, 0.f, 0.f, 0.f};

    STAGE(0, 0);
    STAGE(1, 1);
    CHUNK(0, 4);  CHUNK(1, 4);  CHUNK(2, 4);  CHUNK(3, 4);
    CHUNK(4, 4);  CHUNK(5, 4);  CHUNK(6, 2);  CHUNK(7, 0);
#undef STAGE
#undef COMPUTE
#undef CHUNK

    // relu + bias -> hid LDS (bf16, swizzled). C layout: col=l15, row=lq*4+i
    {
        float b1v = b1[myE * CH + colw];
        int colh = s1s * 64 + colw;
        #pragma unroll
        for (int i = 0; i < 4; i++) {
            int r0 = lq * 4 + i;
            float hv = acc[i] + b1v; hv = hv > 0.f ? hv : 0.f;
            int by = (r0 * 256 + colh * 2) ^ ((r0 & 7) << 4);
            *(unsigned short*)((char*)hid_s + by) = bf1(hv);
        }
    }
    __syncthreads();

    // ---- stage 2: wave w owns o-band [w*128, w*128+128)
    bf16x8 af[2][2];
    #pragma unroll
    for (int s = 0; s < 2; s++)
        #pragma unroll
        for (int ks = 0; ks < 2; ks++) {
            int col = s * 64 + ks * 32 + lq * 8;
            int by = (l15 * 256 + col * 2) ^ ((l15 & 7) << 4);
            af[s][ks] = *(const bf16x8*)((const char*)hid_s + by);
        }

    const unsigned short* W2lo = W2p + (size_t)lo * (CH * 3 * OD);
    const unsigned short* W2hi = W2p + (size_t)hi * (CH * 3 * OD);
    const float* b2lo = b2 + (size_t)lo * 3072;
    const float* b2hi = b2 + (size_t)hi * 3072;

    int   tok_r[4];
    float twx[4], twy[4];
    #pragma unroll
    for (int i = 0; i < 4; i++) {
        int trow = lq * 4 + i;
        tok_r[i] = toks[trow];
        float2 t2 = tw[trow];
        twx[i] = t2.x; twy[i] = t2.y;
    }

    for (int ot = 0; ot < 8; ot++) {
        int o = w * 128 + ot * 16 + l15;
        float xo[4], vo[4];
        #pragma unroll
        for (int i = 0; i < 4; i++) {
            size_t off = (size_t)tok_r[i] * OD + o;
            xo[i] = x[off];
            vo[i] = v[off];
        }
        float muo = mu[o];
        float accVN[4] = {0.f,0.f,0.f,0.f};
        float accGV[4] = {0.f,0.f,0.f,0.f};

        #pragma unroll
        for (int s = 0; s < 2; s++) {
            const unsigned short* W2e = s ? W2hi : W2lo;
            const float* b2e = s ? b2hi : b2lo;
            f32x4 aA = {0.f,0.f,0.f,0.f};
            f32x4 aB = {0.f,0.f,0.f,0.f};
            f32x4 aG = {0.f,0.f,0.f,0.f};
            #pragma unroll
            for (int ks = 0; ks < 2; ks++) {
                int kb = ks * 4 + lq;
                bf16x8 wA = *(const bf16x8*)(W2e + ((size_t)kb * 3072 + o) * 8);
                bf16x8 wB = *(const bf16x8*)(W2e + ((size_t)kb * 3072 + OD + o) * 8);
                bf16x8 wG = *(const bf16x8*)(W2e + ((size_t)kb * 3072 + 2 * OD + o) * 8);
                aA = __builtin_amdgcn_mfma_f32_16x16x32_bf16(af[s][ks], wA, aA, 0, 0, 0);
                aB = __builtin_amdgcn_mfma_f32_16x16x32_bf16(af[s][ks], wB, aB, 0, 0, 0);
                aG = __builtin_amdgcn_mfma_f32_16x16x32_bf16(af[s][ks], wG, aG, 0, 0, 0);
            }
            float ba = b2e[o], bb = b2e[OD + o], bg = b2e[2 * OD + o];
            #pragma unroll
            for (int i = 0; i < 4; i++) {
                float za = aA[i] + ba;
                float zb = aB[i] + bb;
                float zg = aG[i] + bg;
                float alpha = fsigmoid(za);
                float beta  = fsoftplus(zb);
                float gate  = fsigmoid(zg);
                float ws = s ? twy[i] : twx[i];
                float vn_s = alpha * vo[i] - beta * (xo[i] - muo);
                accVN[i] += ws * vn_s;
                accGV[i] += ws * gate * vn_s;
            }
        }
        #pragma unroll
        for (int i = 0; i < 4; i++) {
            if (lq * 4 + i < nt) {
                size_t off = (size_t)tok_r[i] * OD + o;
                out[off]          = xo[i] + 0.1f * accGV[i];
                out[OFF_VN + off] = accVN[i];
            }
        }
    }
}

extern "C" void kernel_launch(void* const* d_in, const int* in_sizes, int n_in,
                              void* d_out, int out_size, void* d_ws, size_t ws_size,
                              hipStream_t stream)
{
    (void)in_sizes; (void)n_in; (void)out_size; (void)ws_size;
    const float* h  = (const float*)d_in[0];
    const float* x  = (const float*)d_in[1];
    const float* v  = (const float*)d_in[2];
    const float* rw = (const float*)d_in[3];
    const float* rb = (const float*)d_in[4];
    const float* mu = (const float*)d_in[5];
    const float* W1 = (const float*)d_in[6];
    const float* b1 = (const float*)d_in[7];
    const float* W2 = (const float*)d_in[8];
    const float* b2 = (const float*)d_in[9];
    float* out = (float*)d_out;

    char* ws = (char*)d_ws;
    int*    pcnt  = (int*)(ws + WS_PCNT);
    int*    total = (int*)(ws + WS_TOTAL);
    int*    table = (int*)(ws + WS_TABLE);
    int*    plist = (int*)(ws + WS_PLIST);
    float2* pwts  = (float2*)(ws + WS_PWTS);
    unsigned short* W1p  = (unsigned short*)(ws + WS_W1P);
    unsigned short* W2p  = (unsigned short*)(ws + WS_W2P);
    unsigned short* ctxb = (unsigned short*)(ws + WS_CTXB);

    hipMemsetAsync(pcnt, 0, 64 * sizeof(int), stream);

    pre_kernel<<<3840, 256, 0, stream>>>(h, x, v, rw, rb, W1, W2,
                                         W1p, W2p, ctxb, out,
                                         pcnt, plist, pwts);
    prefix_kernel<<<1, 64, 0, stream>>>(pcnt, table, total);
    moe_kernel<<<576, 512, 0, stream>>>(x, v, mu, b1, b2, W1p, W2p, ctxb,
                                        pcnt, table, total, plist, pwts, out);
}